// Round 1
// 270.754 us; speedup vs baseline: 1.0334x; 1.0334x over previous
//
#include <hip/hip_runtime.h>
#include <hip/hip_bf16.h>
#include <cstdint>
#include <cstddef>

#define TT 64
#define CC 32
#define FF 16
#define HWSZ 1024
#define NPIX 16384   // B*H*W = 16*32*32

typedef __attribute__((ext_vector_type(8))) short  short8;   // 8 bf16 (4 VGPRs)
typedef __attribute__((ext_vector_type(4))) short  short4v;  // 4 bf16 (2 VGPRs)
typedef __attribute__((ext_vector_type(4))) float  f32x4;    // MFMA accumulator

__device__ __forceinline__ float bf2f(unsigned int u16) {
  union { unsigned int u; float f; } c;
  c.u = u16 << 16;
  return c.f;
}
__device__ __forceinline__ unsigned int f2bf(float f) {
  union { float f; unsigned int u; } c;
  c.f = f;
  unsigned int u = c.u;
  return (u + 0x7fffu + ((u >> 16) & 1u)) >> 16;  // RNE
}
// packed fp32x2 -> bf16x2
__device__ __forceinline__ unsigned int pkbf(float a, float b) {
  float2 f2; f2.x = a; f2.y = b;
  __hip_bfloat162 h = __float22bfloat162_rn(f2);
  union { __hip_bfloat162 h; unsigned int u; } c; c.h = h;
  return c.u;
}
__device__ __forceinline__ float clamp01(float x) {
  return fminf(fmaxf(x, 0.0f), 1.0f);
}

#define L2E2 2.8853900817779268f   // 2*log2(e):  tanh(v) = 1 - 2/(exp2(v*L2E2)+1)
__device__ __forceinline__ float tanh_e2(float e2arg) {
  const float e = __builtin_exp2f(e2arg);
  const float t = __builtin_amdgcn_rcpf(e + 1.0f);
  return fmaf(-2.0f, t, 1.0f);
}

// ---------------------------------------------------------------------------
// Fold the 3 linear layers: Wc = w1@w2@w3 [32x10], bc = b1@w2@w3 + b2@w3 + b3.
// ---------------------------------------------------------------------------
__global__ __launch_bounds__(512) void fold_kernel(
    const float* __restrict__ w1, const float* __restrict__ b1,
    const float* __restrict__ w2, const float* __restrict__ b2,
    const float* __restrict__ w3, const float* __restrict__ b3,
    float* __restrict__ Wc, float* __restrict__ bc)
{
  __shared__ float w23[16 * 10];
  __shared__ float bb2[16];
  const int t = threadIdx.x;

  if (t < 160) {
    const int k = t / 10, j = t % 10;
    float s = 0.0f;
    #pragma unroll
    for (int m = 0; m < 16; ++m) s = fmaf(w2[k * 16 + m], w3[m * 10 + j], s);
    w23[t] = s;
  }
  if (t < 16) {
    float s = b2[t];
    #pragma unroll
    for (int m = 0; m < 16; ++m) s = fmaf(b1[m], w2[m * 16 + t], s);
    bb2[t] = s;
  }
  __syncthreads();
  if (t < 320) {
    const int k = t / 10, j = t % 10;
    float s = 0.0f;
    #pragma unroll
    for (int m = 0; m < 16; ++m) s = fmaf(w1[k * 16 + m], w23[m * 10 + j], s);
    Wc[t] = s;
  }
  if (t < 10) {
    float s = b3[t];
    #pragma unroll
    for (int m = 0; m < 16; ++m) s = fmaf(bb2[m], w3[m * 10 + t], s);
    bc[t] = s;
  }
}

// ---------------------------------------------------------------------------
// Transposed-MFMA LSTM, zero LDS, ZERO cross-lane exchange.
//   z^T[f][px] : A = weights^T (m=f, k=c), B = x/h (n=px, k=c)
// Recurrent MFMA uses 16x16x16 (K = F = 16, no padding):
//   B-frag: lane(q,p) holds h[k=4q+j][px=p], j=0..3
//   C-frag: lane(q,p) holds h_new[f=4q+r][px=p], r=0..3
// -> identical lane mapping: epilogue output packs straight into the next
//    step's B operand with 2 cvt_pk. No ds_bpermute, no LDS at all.
// x@W (K=32) stays 16x16x32 off-path; same C layout feeds zx as C operand.
// x loads prefetched 4 steps deep (4 named register buffers, static wiring).
// ---------------------------------------------------------------------------
__global__ __launch_bounds__(256, 2) void lstm_kernel(
    const float* __restrict__ x,
    const float* __restrict__ Wf, const float* __restrict__ Uf, const float* __restrict__ bfp,
    const float* __restrict__ Wb, const float* __restrict__ Ub, const float* __restrict__ bbp,
    unsigned short* __restrict__ hf_out, unsigned short* __restrict__ hb_out)
{
  const int dir = blockIdx.y;
  const float* __restrict__ Wp = dir ? Wb : Wf;
  const float* __restrict__ Up = dir ? Ub : Uf;
  const float* __restrict__ bp = dir ? bbp : bfp;
  unsigned short* __restrict__ hout = dir ? hb_out : hf_out;

  const int tid  = threadIdx.x;
  const int lane = tid & 63;
  const int wid  = tid >> 6;       // wave in block, 0..3 (waves independent)
  const int quad = lane >> 4;      // 0..3
  const int l15  = lane & 15;

  const int px  = (blockIdx.x * 4 + wid) * 16 + l15;   // this lane's pixel (N role)
  const int b   = px >> 10;
  const int hwi = px & 1023;

  // ---- A fragments (weights^T), loaded once ----
  // AW[nt] (K=32): lane(q,p): W[k=8q+j][nt*16+p]   (k = input channel, m = filter p)
  // AU[nt] (K=16): lane(q,p): U[k=4q+j][nt*16+p]   (no K padding)
  short8  AW[4];
  short4v AU[4];
  #pragma unroll
  for (int nt = 0; nt < 4; ++nt) {
    short8 vw;
    #pragma unroll
    for (int j = 0; j < 8; ++j) {
      const int k   = quad * 8 + j;
      const int col = nt * 16 + l15;
      vw[j] = (short)f2bf(Wp[k * 64 + col]);
    }
    AW[nt] = vw;
    short4v vu;
    #pragma unroll
    for (int j = 0; j < 4; ++j) {
      const int k   = quad * 4 + j;
      const int col = nt * 16 + l15;
      vu[j] = (short)f2bf(Up[k * 64 + col]);
    }
    AU[nt] = vu;
  }

  // biases: lane(q,p) owns f = q*4+r (rows of C)
  float bi[4], bfv[4], bgl[4], bo[4];
  #pragma unroll
  for (int r = 0; r < 4; ++r) {
    const int f = quad * 4 + r;
    bi[r]  = fmaf(bp[ 0 + f], 0.2f, 0.5f);
    bfv[r] = fmaf(bp[16 + f], 0.2f, 0.5f);
    bgl[r] = bp[32 + f] * L2E2;
    bo[r]  = fmaf(bp[48 + f], 0.2f, 0.5f);
  }

  float cst[4] = {0.f, 0.f, 0.f, 0.f};
  union BU  { short8  s8; int i[4]; };
  union BH  { short4v s4; int i[2]; };
  BH Bh; Bh.i[0] = 0; Bh.i[1] = 0;     // h = 0 at s=0

  // strength-reduced byte offsets
  const int t0 = dir ? (TT - 1) : 0;
  const unsigned int pos0 = (unsigned int)((b * TT + t0) * HWSZ + hwi);
  const int xstep = dir ? -(HWSZ * CC * 4) : (HWSZ * CC * 4);
  const int hstep = dir ? -(HWSZ * 32) : (HWSZ * 32);
  unsigned int hob = pos0 * 32 + quad * 8;     // h store (8 B per lane, all lanes)

  const char* xb = (const char*)x;
  char* hbb = (char*)hout;

  // ---- prologue: load x[t0..t0+4]; compute zx(x[0-th step]) ----
  const unsigned int xo0 = pos0 * (CC * 4) + quad * 32;
  float4 t0a = *reinterpret_cast<const float4*>(xb + xo0);
  float4 t0b = *reinterpret_cast<const float4*>(xb + xo0 + 16);
  unsigned int xoff = xo0 + xstep;
  float4 b1a = *reinterpret_cast<const float4*>(xb + xoff);
  float4 b1b = *reinterpret_cast<const float4*>(xb + xoff + 16);
  xoff += xstep;
  float4 b2a = *reinterpret_cast<const float4*>(xb + xoff);
  float4 b2b = *reinterpret_cast<const float4*>(xb + xoff + 16);
  xoff += xstep;
  float4 b3a = *reinterpret_cast<const float4*>(xb + xoff);
  float4 b3b = *reinterpret_cast<const float4*>(xb + xoff + 16);
  xoff += xstep;                                         // -> x[4]
  float4 b0a = *reinterpret_cast<const float4*>(xb + xoff);
  float4 b0b = *reinterpret_cast<const float4*>(xb + xoff + 16);

  f32x4 zx[4];
  {
    BU ax;
    ax.i[0] = pkbf(t0a.x, t0a.y); ax.i[1] = pkbf(t0a.z, t0a.w);
    ax.i[2] = pkbf(t0b.x, t0b.y); ax.i[3] = pkbf(t0b.z, t0b.w);
    const f32x4 zz = {0.f, 0.f, 0.f, 0.f};
    #pragma unroll
    for (int nt = 0; nt < 4; ++nt)
      zx[nt] = __builtin_amdgcn_mfma_f32_16x16x32_bf16(AW[nt], ax.s8, zz, 0, 0, 0);
  }

  // Per step: consume buffer (s+1)&3 (holds x[s+1]) for next zx, then reload
  // it with x[s+5] (address clamped at the last timestep; results unused).
#define STEP(S, BA, BB) do {                                                   \
    /* on-path: z = zx + h @ U, K=16, single MFMA depth, no exchange */        \
    f32x4 z_[4];                                                               \
    _Pragma("unroll")                                                          \
    for (int nt = 0; nt < 4; ++nt)                                             \
      z_[nt] = __builtin_amdgcn_mfma_f32_16x16x16bf16_1k(AU[nt], Bh.s4, zx[nt], 0, 0, 0); \
    /* off-path: zx for step S+1 from buffer holding x[S+1] */                 \
    {                                                                          \
      BU ax;                                                                   \
      ax.i[0] = pkbf(BA.x, BA.y); ax.i[1] = pkbf(BA.z, BA.w);                  \
      ax.i[2] = pkbf(BB.x, BB.y); ax.i[3] = pkbf(BB.z, BB.w);                  \
      const f32x4 zzv = {0.f, 0.f, 0.f, 0.f};                                  \
      _Pragma("unroll")                                                        \
      for (int nt = 0; nt < 4; ++nt)                                           \
        zx[nt] = __builtin_amdgcn_mfma_f32_16x16x32_bf16(AW[nt], ax.s8, zzv, 0, 0, 0); \
    }                                                                          \
    /* prefetch x[S+5] into the buffer just consumed (4-deep pipeline) */      \
    if ((S) + 5 < TT) xoff += xstep;                                           \
    BA = *reinterpret_cast<const float4*>(xb + xoff);                          \
    BB = *reinterpret_cast<const float4*>(xb + xoff + 16);                     \
    /* epilogue: lane(q,p) owns (f = 4q+r, px = p) */                          \
    float hv[4];                                                               \
    _Pragma("unroll")                                                          \
    for (int r = 0; r < 4; ++r) {                                              \
      const float ig = clamp01(fmaf(z_[0][r], 0.2f, bi[r]));                   \
      const float fg = clamp01(fmaf(z_[1][r], 0.2f, bfv[r]));                  \
      const float og = clamp01(fmaf(z_[3][r], 0.2f, bo[r]));                   \
      const float gg = tanh_e2(fmaf(z_[2][r], L2E2, bgl[r]));                  \
      cst[r] = fmaf(fg, cst[r], ig * gg);                                      \
      hv[r]  = og * tanh_e2(cst[r] * L2E2);                                    \
    }                                                                          \
    /* pack: C layout == next B-frag layout; 2 cvt_pk and we're done */        \
    Bh.i[0] = (int)pkbf(hv[0], hv[1]);   /* k = 4q, 4q+1 */                    \
    Bh.i[1] = (int)pkbf(hv[2], hv[3]);   /* k = 4q+2, 4q+3 */                  \
    /* store h[t]: every lane writes 8 B (features 4q..4q+3 of pixel p) */     \
    *reinterpret_cast<int2*>(hbb + hob) = make_int2(Bh.i[0], Bh.i[1]);         \
    hob += hstep;                                                              \
  } while (0)

  for (int sb = 0; sb < TT; sb += 4) {
    STEP(sb + 0, b1a, b1b);
    STEP(sb + 1, b2a, b2b);
    STEP(sb + 2, b3a, b3b);
    STEP(sb + 3, b0a, b0b);
  }
#undef STEP
}

// ---------------------------------------------------------------------------
// Dense via MFMA: out[1M x 10] = [hf|hb] @ Wc + bc.  Wave = 16 positions/tile.
// A-frag straight from the h buffers (16B/lane). Wc as bf16 hi+lo B-frags
// (2 chained MFMAs => fp32-accurate weights). Bias in the C init.
// ---------------------------------------------------------------------------
__global__ __launch_bounds__(256) void dense_kernel(
    const unsigned short* __restrict__ hf, const unsigned short* __restrict__ hb,
    const float* __restrict__ Wc, const float* __restrict__ bc,
    float* __restrict__ out)
{
  const int tid  = threadIdx.x;
  const int lane = tid & 63;
  const int quad = lane >> 4;
  const int l15  = lane & 15;

  // B fragments: B[n=l15][k=8*quad+j], k<16 -> hf features, k>=16 -> hb
  short8 Bhi, Blo;
  #pragma unroll
  for (int j = 0; j < 8; ++j) {
    const int k = quad * 8 + j;
    const float v  = (l15 < 10) ? Wc[k * 10 + l15] : 0.0f;
    const unsigned int hi = f2bf(v);
    const float lo = v - bf2f(hi);
    Bhi[j] = (short)hi;
    Blo[j] = (short)f2bf(lo);
  }
  const float bcv = (l15 < 10) ? bc[l15] : 0.0f;

  const unsigned short* __restrict__ src = (quad & 2) ? hb : hf;
  const unsigned int lsub = (quad & 1) * 8;

  const unsigned int gw = (blockIdx.x * 256 + tid) >> 6;  // global wave 0..8191

  #pragma unroll
  for (int i = 0; i < 8; ++i) {
    const unsigned int tile  = gw * 8 + i;
    const unsigned int pos16 = tile * 16 + l15;
    const short8 A = *reinterpret_cast<const short8*>(src + pos16 * 16 + lsub);

    f32x4 acc = {bcv, bcv, bcv, bcv};
    acc = __builtin_amdgcn_mfma_f32_16x16x32_bf16(A, Bhi, acc, 0, 0, 0);
    acc = __builtin_amdgcn_mfma_f32_16x16x32_bf16(A, Blo, acc, 0, 0, 0);

    if (l15 < 10) {
      const unsigned int rowbase = tile * 16 + quad * 4;
      #pragma unroll
      for (int r = 0; r < 4; ++r) {
        out[(size_t)(rowbase + r) * 10 + l15] = acc[r];
      }
    }
  }
}

extern "C" void kernel_launch(void* const* d_in, const int* in_sizes, int n_in,
                              void* d_out, int out_size, void* d_ws, size_t ws_size,
                              hipStream_t stream) {
  const float* x   = (const float*)d_in[0];
  const float* Wf  = (const float*)d_in[1];
  const float* Uf  = (const float*)d_in[2];
  const float* bfp = (const float*)d_in[3];
  const float* Wb  = (const float*)d_in[4];
  const float* Ub  = (const float*)d_in[5];
  const float* bbp = (const float*)d_in[6];
  const float* w1  = (const float*)d_in[7];
  const float* b1  = (const float*)d_in[8];
  const float* w2  = (const float*)d_in[9];
  const float* b2  = (const float*)d_in[10];
  const float* w3  = (const float*)d_in[11];
  const float* b3  = (const float*)d_in[12];

  unsigned short* hfbuf = (unsigned short*)d_ws;                 // 16M bf16 = 33.5 MB
  unsigned short* hbbuf = hfbuf + (size_t)NPIX * TT * FF;        // +33.5 MB
  float* Wc = (float*)(hbbuf + (size_t)NPIX * TT * FF);          // 320 floats
  float* bc = Wc + 320;                                          // 10 floats

  fold_kernel<<<1, 512, 0, stream>>>(w1, b1, w2, b2, w3, b3, Wc, bc);

  // 256 blocks x 4 waves x 16 px = 16384 px, x2 directions
  lstm_kernel<<<dim3(256, 2), 256, 0, stream>>>(x, Wf, Uf, bfp, Wb, Ub, bbp, hfbuf, hbbuf);

  // 1M positions / 16-per-wave / 8-tiles-per-wave = 8192 waves = 2048 blocks
  dense_kernel<<<2048, 256, 0, stream>>>(hfbuf, hbbuf, Wc, bc, (float*)d_out);
}